// Round 7
// baseline (3906.068 us; speedup 1.0000x reference)
//
#include <hip/hip_runtime.h>
#include <hip/hip_bf16.h>
#include <math.h>

#define NODES   325
#define TOPK    8
#define B_SZ    8
#define T_LEN   64
#define EPS     1e-5f
#define NTOK    ((size_t)B_SZ * T_LEN * NODES)   /* 166,400 */

__device__ __forceinline__ float waveSum64(float v){
  #pragma unroll
  for(int m=1;m<64;m<<=1) v += __shfl_xor(v, m, 64);
  return v;
}
__device__ __forceinline__ float groupSum16(float v){
  v += __shfl_xor(v, 1, 64);
  v += __shfl_xor(v, 2, 64);
  v += __shfl_xor(v, 4, 64);
  v += __shfl_xor(v, 8, 64);
  return v;
}
__device__ __forceinline__ float dot64(const float* __restrict__ s,
                                       const float* __restrict__ w, float acc){
  #pragma unroll
  for(int q=0;q<64;q++) acc = fmaf(s[q], w[q], acc);
  return acc;
}
__device__ __forceinline__ float dot128(const float* __restrict__ s,
                                        const float* __restrict__ w, float acc){
  #pragma unroll
  for(int q=0;q<128;q++) acc = fmaf(s[q], w[q], acc);
  return acc;
}

// ---------------- Mamba per-sequence kernel (R6-validated) ----------------
// grid = B*NODES blocks, 128 threads; thread d owns D_INNER channel d.
__global__ __launch_bounds__(128)
void opt_mamba(const float* __restrict__ x,
               const float* __restrict__ ln1_g, const float* __restrict__ ln1_b,
               const float* __restrict__ in_w,
               const float* __restrict__ conv_w, const float* __restrict__ conv_b,
               const float* __restrict__ xp_w,
               const float* __restrict__ dt_w, const float* __restrict__ dt_b,
               const float* __restrict__ A_log, const float* __restrict__ Dss,
               const float* __restrict__ out_w,
               float* __restrict__ xT)
{
  const int bn  = blockIdx.x;
  const int b   = bn / NODES;
  const int n   = bn % NODES;
  const int tid = threadIdx.x;
  const int d   = tid;

  __shared__ float s_x[64];
  __shared__ float s_h[64];
  __shared__ float s_xc[128];
  __shared__ float s_dbl[36];
  __shared__ float s_y[128];

  float A_d[16], hs[16];
  #pragma unroll
  for(int s=0;s<16;s++){ A_d[s] = -__expf(A_log[d*16+s]); hs[s] = 0.f; }
  float cw0 = conv_w[d*4+0], cw1 = conv_w[d*4+1];
  float cw2 = conv_w[d*4+2], cw3 = conv_w[d*4+3];
  float dtw0 = dt_w[d*4+0], dtw1 = dt_w[d*4+1];
  float dtw2 = dt_w[d*4+2], dtw3 = dt_w[d*4+3];
  float cb  = conv_b[d], dtb = dt_b[d], Dd = Dss[d];
  float g_ln = 0.f, b_ln = 0.f;
  if(tid < 64){ g_ln = ln1_g[tid]; b_ln = ln1_b[tid]; }
  float xm1 = 0.f, xm2 = 0.f, xm3 = 0.f;   // xi history for causal conv

  for(int t=0; t<T_LEN; t++){
    __syncthreads();
    const size_t tok = (size_t)(b*T_LEN + t)*NODES + n;

    if(tid < 64){
      float v = x[tok*64 + tid];
      s_x[tid] = v;
      float m   = waveSum64(v) * (1.f/64.f);
      float c   = v - m;
      float var = waveSum64(c*c) * (1.f/64.f);
      s_h[tid] = c * rsqrtf(var + EPS) * g_ln + b_ln;
    }
    __syncthreads();

    // in_proj: thread d computes xi (row d) and z (row d+128)
    float xi = dot64(s_h, in_w + d*64,       0.f);
    float zz = dot64(s_h, in_w + (d+128)*64, 0.f);

    // depthwise causal conv (window 4) + silu
    float xcv = cb + cw0*xm3 + cw1*xm2 + cw2*xm1 + cw3*xi;
    xm3 = xm2; xm2 = xm1; xm1 = xi;
    float xc = xcv / (1.f + __expf(-xcv));
    s_xc[d] = xc;
    __syncthreads();

    // x_proj: 36 rows of dot-128
    if(tid < 36) s_dbl[tid] = dot128(s_xc, xp_w + tid*128, 0.f);
    __syncthreads();

    // dt = softplus(dt_raw @ dt_w.T + dt_b)
    float dtv = dtb;
    dtv = fmaf(s_dbl[0], dtw0, dtv);
    dtv = fmaf(s_dbl[1], dtw1, dtv);
    dtv = fmaf(s_dbl[2], dtw2, dtv);
    dtv = fmaf(s_dbl[3], dtw3, dtv);
    dtv = fmaxf(dtv, 0.f) + log1pf(__expf(-fabsf(dtv)));

    // selective scan update + readout
    float dx = dtv * xc;
    float y  = 0.f;
    #pragma unroll
    for(int s=0;s<16;s++){
      float dA = __expf(dtv * A_d[s]);
      hs[s] = fmaf(hs[s], dA, dx * s_dbl[4+s]);
      y     = fmaf(hs[s], s_dbl[20+s], y);
    }
    y = y + Dd * xc;
    y = y * (zz / (1.f + __expf(-zz)));   // * silu(z)
    s_y[d] = y;
    __syncthreads();

    // out_proj + residual -> xT (fp32)
    if(tid < 64){
      float acc = dot128(s_y, out_w + tid*128, 0.f);
      xT[tok*64 + tid] = s_x[tid] + acc;
    }
  }
}

// ---------------- Graph attention + gate + LN2 (R6-validated) ----------------
// grid = NTOK blocks, 64 threads; writes fp32 directly to d_out.
__global__ __launch_bounds__(64)
void opt_attn(const float* __restrict__ xT, const int* __restrict__ nbr,
              const float* __restrict__ q_w, const float* __restrict__ q_b,
              const float* __restrict__ k_w, const float* __restrict__ k_b,
              const float* __restrict__ v_w, const float* __restrict__ v_b,
              const float* __restrict__ o_w, const float* __restrict__ o_b,
              const float* __restrict__ g1_w, const float* __restrict__ g1_b,
              const float* __restrict__ g2_w, const float* __restrict__ g2_b,
              const float* __restrict__ ln2_g, const float* __restrict__ ln2_b,
              float* __restrict__ out)
{
  const int idx = blockIdx.x;           // (b*T + t)*NODES + n
  const int n   = idx % NODES;
  const int bt  = idx / NODES;
  const int j   = threadIdx.x;

  __shared__ float s_x[64];
  __shared__ float s_nb[TOPK][64];
  __shared__ float s_og[64];
  __shared__ float s_gate;

  float xv = xT[(size_t)idx*64 + j];
  s_x[j] = xv;
  const int base = bt * NODES;
  #pragma unroll
  for(int k=0;k<TOPK;k++){
    int nb2 = nbr[n*TOPK + k];
    s_nb[k][j] = xT[(size_t)(base + nb2)*64 + j];
  }
  __syncthreads();

  // Q projection for own token
  float Qj = dot64(s_x, q_w + j*64, q_b[j]);

  // neighbors' K/V recomputed; head-wise scores via 16-lane reductions
  float sc[TOPK], vv[TOPK];
  #pragma unroll
  for(int k=0;k<TOPK;k++){
    float Kk = dot64(s_nb[k], k_w + j*64, k_b[j]);
    vv[k]    = dot64(s_nb[k], v_w + j*64, v_b[j]);
    sc[k]    = groupSum16(Qj * Kk) * 0.25f;   // hd^-0.5 = 1/4
  }
  float m = sc[0];
  #pragma unroll
  for(int k=1;k<TOPK;k++) m = fmaxf(m, sc[k]);
  float ssum = 0.f;
  #pragma unroll
  for(int k=0;k<TOPK;k++){ sc[k] = __expf(sc[k]-m); ssum += sc[k]; }
  float inv = 1.f/ssum;
  float og = 0.f;
  #pragma unroll
  for(int k=0;k<TOPK;k++) og = fmaf(sc[k]*inv, vv[k], og);
  s_og[j] = og;
  __syncthreads();

  // o projection
  float xg = dot64(s_og, o_w + j*64, o_b[j]);

  // scalar gate: sigmoid(gelu(x@g1^T+b1) @ g2^T + b2)
  if(j < 16){
    float u = dot64(s_x, g1_w + j*64, g1_b[j]);
    u = 0.5f * u * (1.f + erff(u * 0.70710678118654752f));   // exact gelu
    float contrib = groupSum16(u * g2_w[j]);
    if(j == 0) s_gate = 1.f / (1.f + __expf(-(contrib + g2_b[0])));
  }
  __syncthreads();

  float gg = s_gate;
  float o  = xv + gg * (xg - xv);

  // LN2 across the 64 lanes
  float mm  = waveSum64(o) * (1.f/64.f);
  float c   = o - mm;
  float var = waveSum64(c*c) * (1.f/64.f);
  out[(size_t)idx*64 + j] = c * rsqrtf(var + EPS) * ln2_g[j] + ln2_b[j];
}

extern "C" void kernel_launch(void* const* d_in, const int* in_sizes, int n_in,
                              void* d_out, int out_size, void* d_ws, size_t ws_size,
                              hipStream_t stream)
{
  const float* x      = (const float*)d_in[0];
  const int*   nbr    = (const int*  )d_in[1];
  const float* ln1_g  = (const float*)d_in[2];
  const float* ln1_b  = (const float*)d_in[3];
  const float* in_w   = (const float*)d_in[4];
  const float* conv_w = (const float*)d_in[5];
  const float* conv_b = (const float*)d_in[6];
  const float* xp_w   = (const float*)d_in[7];
  const float* dt_w   = (const float*)d_in[8];
  const float* dt_b   = (const float*)d_in[9];
  const float* A_log  = (const float*)d_in[10];
  const float* Dss    = (const float*)d_in[11];
  const float* out_w  = (const float*)d_in[12];
  const float* q_w    = (const float*)d_in[13];
  const float* q_b    = (const float*)d_in[14];
  const float* k_w    = (const float*)d_in[15];
  const float* k_b    = (const float*)d_in[16];
  const float* v_w    = (const float*)d_in[17];
  const float* v_b    = (const float*)d_in[18];
  const float* o_w    = (const float*)d_in[19];
  const float* o_b    = (const float*)d_in[20];
  const float* g1_w   = (const float*)d_in[21];
  const float* g1_b   = (const float*)d_in[22];
  const float* g2_w   = (const float*)d_in[23];
  const float* g2_b   = (const float*)d_in[24];
  const float* ln2_g  = (const float*)d_in[25];
  const float* ln2_b  = (const float*)d_in[26];

  float* xT   = (float*)d_ws;          // NTOK*64 fp32 = 42.6 MB (ws >= 85 MB proven in R6)
  float* outp = (float*)d_out;         // fp32 output — the reference's dtype

  opt_mamba<<<dim3(B_SZ*NODES), dim3(128), 0, stream>>>(
      x, ln1_g, ln1_b, in_w, conv_w, conv_b, xp_w, dt_w, dt_b, A_log, Dss, out_w, xT);

  opt_attn<<<dim3((unsigned)NTOK), dim3(64), 0, stream>>>(
      xT, nbr, q_w, q_b, k_w, k_b, v_w, v_b, o_w, o_b,
      g1_w, g1_b, g2_w, g2_b, ln2_g, ln2_b, outp);
}